// Round 4
// baseline (294.480 us; speedup 1.0000x reference)
//
#include <hip/hip_runtime.h>

// MSE-sum loss: out[0] = 0.5 * sum((a[i]-b[i])^2), n = 40e6 fp32 per input.
//
// R9 analysis: R8 (burst grouping, stream decorrelation, 128 KB blocks) was
// NULL (294.5 -> 293.8). Pattern is not the lever. Evidence: write-only fill
// 6.86 TB/s; no-nt read 2.86; nt read 3.9 regardless of structure/pattern;
// occupancy ample (256 KB in flight/CU vs ~9.5 KB needed). R1 counters show
// ~zero WRITE_SIZE during stage1 -> poison-fill writeback NOT contending.
// Remaining suspect: L2/InfinityCache miss-service path (~4 TB/s), since nt
// only hints eviction but still routes through the caches.
// Probe: system-scope streaming reads -- inline asm global_load_dwordx4 with
// "sc0 sc1 nt" (bypass L1/L2/MALL). 8 loads + s_waitcnt vmcnt(0) per asm
// block (early-clobber outputs: no addr/data aliasing; wait inside block:
// no rule-#18 hoisting hazard). Same geometry as proven 82 us kernel.
// Prediction: stage1 ~55-65 us, total ~265-280 if cache path was the cap;
// total ~294 => HBM read roofline (declare next round); ~315 => sc-overhead,
// revert.

typedef float fvec4 __attribute__((ext_vector_type(4)));

#define V4_PER_BLOCK 2048L   // 256 threads * 8 float4 each, per input array

__global__ __launch_bounds__(256) void mse_stage1(const fvec4* __restrict__ a4,
                                                  const fvec4* __restrict__ b4,
                                                  float* __restrict__ partial,
                                                  long n4) {
    const int t = threadIdx.x;
    const long base = (long)blockIdx.x * V4_PER_BLOCK;

    float acc0 = 0.0f, acc1 = 0.0f, acc2 = 0.0f, acc3 = 0.0f;

    if (base + V4_PER_BLOCK <= n4) {
        #pragma unroll
        for (int r = 0; r < 2; ++r) {
            const fvec4* pa = a4 + base + (long)r * 1024 + t;
            const fvec4* pb = b4 + base + (long)r * 1024 + t;
            fvec4 x0, x1, x2, x3, y0, y1, y2, y3;
            // System-scope streaming loads: bypass L1/L2/MALL, pure HBM read.
            // waitcnt inside the block => data valid at block end, no
            // compiler-hoisting hazard. Early-clobber outs => no aliasing
            // with the 64-bit address inputs while loads are in flight.
            asm volatile(
                "global_load_dwordx4 %0, %8,  off sc0 sc1 nt\n\t"
                "global_load_dwordx4 %4, %12, off sc0 sc1 nt\n\t"
                "global_load_dwordx4 %1, %9,  off sc0 sc1 nt\n\t"
                "global_load_dwordx4 %5, %13, off sc0 sc1 nt\n\t"
                "global_load_dwordx4 %2, %10, off sc0 sc1 nt\n\t"
                "global_load_dwordx4 %6, %14, off sc0 sc1 nt\n\t"
                "global_load_dwordx4 %3, %11, off sc0 sc1 nt\n\t"
                "global_load_dwordx4 %7, %15, off sc0 sc1 nt\n\t"
                "s_waitcnt vmcnt(0)"
                : "=&v"(x0), "=&v"(x1), "=&v"(x2), "=&v"(x3),
                  "=&v"(y0), "=&v"(y1), "=&v"(y2), "=&v"(y3)
                : "v"(pa), "v"(pa + 256), "v"(pa + 512), "v"(pa + 768),
                  "v"(pb), "v"(pb + 256), "v"(pb + 512), "v"(pb + 768));

            fvec4 d;
            d = x0 - y0; acc0 = fmaf(d.x, d.x, acc0); acc1 = fmaf(d.y, d.y, acc1);
                         acc2 = fmaf(d.z, d.z, acc2); acc3 = fmaf(d.w, d.w, acc3);
            d = x1 - y1; acc0 = fmaf(d.x, d.x, acc0); acc1 = fmaf(d.y, d.y, acc1);
                         acc2 = fmaf(d.z, d.z, acc2); acc3 = fmaf(d.w, d.w, acc3);
            d = x2 - y2; acc0 = fmaf(d.x, d.x, acc0); acc1 = fmaf(d.y, d.y, acc1);
                         acc2 = fmaf(d.z, d.z, acc2); acc3 = fmaf(d.w, d.w, acc3);
            d = x3 - y3; acc0 = fmaf(d.x, d.x, acc0); acc1 = fmaf(d.y, d.y, acc1);
                         acc2 = fmaf(d.z, d.z, acc2); acc3 = fmaf(d.w, d.w, acc3);
        }
    } else {
        // Tail block only (uniform branch): guarded builtin-nt loads.
        #pragma unroll
        for (int u = 0; u < 8; ++u) {
            const long i = base + (long)u * 256 + t;
            if (i < n4) {
                fvec4 xv = __builtin_nontemporal_load(&a4[i]);
                fvec4 yv = __builtin_nontemporal_load(&b4[i]);
                fvec4 d = xv - yv;
                acc0 = fmaf(d.x, d.x, acc0);
                acc1 = fmaf(d.y, d.y, acc1);
                acc2 = fmaf(d.z, d.z, acc2);
                acc3 = fmaf(d.w, d.w, acc3);
            }
        }
    }

    float acc = (acc0 + acc1) + (acc2 + acc3);

    // wave-64 shuffle reduction
    #pragma unroll
    for (int off = 32; off > 0; off >>= 1)
        acc += __shfl_down(acc, off, 64);

    __shared__ float wave_sums[4];
    const int lane = t & 63;
    const int wid  = t >> 6;
    if (lane == 0) wave_sums[wid] = acc;
    __syncthreads();

    if (t == 0)
        partial[blockIdx.x] = (wave_sums[0] + wave_sums[1]) + (wave_sums[2] + wave_sums[3]);
}

__global__ __launch_bounds__(256) void mse_stage2(const float* __restrict__ partial,
                                                  float* __restrict__ out,
                                                  int m) {
    float acc = 0.0f;
    for (int i = threadIdx.x; i < m; i += 256)
        acc += partial[i];

    #pragma unroll
    for (int off = 32; off > 0; off >>= 1)
        acc += __shfl_down(acc, off, 64);

    __shared__ float wave_sums[4];
    const int lane = threadIdx.x & 63;
    const int wid  = threadIdx.x >> 6;
    if (lane == 0) wave_sums[wid] = acc;
    __syncthreads();

    if (threadIdx.x == 0)
        out[0] = 0.5f * ((wave_sums[0] + wave_sums[1]) + (wave_sums[2] + wave_sums[3]));
}

extern "C" void kernel_launch(void* const* d_in, const int* in_sizes, int n_in,
                              void* d_out, int out_size, void* d_ws, size_t ws_size,
                              hipStream_t stream) {
    const fvec4* a4 = (const fvec4*)d_in[0];
    const fvec4* b4 = (const fvec4*)d_in[1];
    float* out = (float*)d_out;
    float* partial = (float*)d_ws;

    const long n = (long)in_sizes[0];        // 40,000,000 floats per input
    const long n4 = n >> 2;                  // 10,000,000 float4 groups (n % 4 == 0)
    const int blocks = (int)((n4 + V4_PER_BLOCK - 1) / V4_PER_BLOCK);   // 4883

    mse_stage1<<<blocks, 256, 0, stream>>>(a4, b4, partial, n4);
    mse_stage2<<<1, 256, 0, stream>>>(partial, out, blocks);
}